// Round 7
// baseline (55.910 us; speedup 1.0000x reference)
//
#include <hip/hip_runtime.h>
#include <math.h>

#define N_DENSE  13
#define N_SPARSE 26
#define VOCAB    100000
#define EMB      64
#define NH       12
#define NPAIR    325
#define NTILE    21      // ceil(325/16) pair tiles
#define EBSTR    72      // u16 per eb_s row: 144B (16B-aligned, bank-spread)
#define ETSTR    32      // u16 per et_s row: 64B, XOR-swizzled slots
#define SSTR     40      // u16 per S row: 80B (16B-aligned, bank-spread)
#define NPADH    336     // logit slots (21*16)
#define TEMP_INV 10.0f

typedef __attribute__((ext_vector_type(8))) _Float16 f16x8;
typedef __attribute__((ext_vector_type(4))) float    f32x4;

// DPP row_shr reduction within each 16-lane row; result lands in lane (row base + 15).
#define DPP_STEP(x, ctrl)                                                        \
    x += __int_as_float(__builtin_amdgcn_update_dpp(                            \
            0, __float_as_int(x), ctrl, 0xF, 0xF, true))
#define DPP_ROWRED(x) do { DPP_STEP(x, 0x111); DPP_STEP(x, 0x112);              \
                           DPP_STEP(x, 0x114); DPP_STEP(x, 0x118); } while (0)

__global__ __launch_bounds__(128, 4) void afm_kernel(
    const float* __restrict__ dense_x,
    const int*   __restrict__ sparse_idx,
    const float* __restrict__ emb,
    const float* __restrict__ attn_W,
    const float* __restrict__ attn_b,
    const float* __restrict__ proj_W,
    const float* __restrict__ proj_b,
    const float* __restrict__ lin_W,
    const float* __restrict__ lin_b,
    const float* __restrict__ pred_W,
    const float* __restrict__ pred_b,
    float* __restrict__ out)
{
    const int tid  = threadIdx.x;
    const int lane = tid & 63;
    const int wv   = tid >> 6;        // wave = row slot (2 rows/block)
    const int q    = lane >> 4;       // MFMA k-group
    const int c16  = lane & 15;       // MFMA row/col-16 index
    const int row  = __builtin_amdgcn_readfirstlane(blockIdx.x * 2 + wv);

    __shared__ __align__(16) unsigned short eb_s[2][N_SPARSE][EBSTR]; // e row-major f16
    __shared__ __align__(16) unsigned short et_s[2][EMB][ETSTR];      // e^T f16, XOR-swz
    __shared__ __align__(16) unsigned short S_s[2][32][SSTR];         // symmetric scores
    __shared__ __align__(16) unsigned short expv_s[2][NPADH];         // parked logits f16

    // ---- zero et (4 KB) and S (2.5 KB) for this wave's slot ----
    {
        const uint4 z = {0u, 0u, 0u, 0u};
        uint4* etb = reinterpret_cast<uint4*>(&et_s[wv][0][0]);
        #pragma unroll
        for (int k = 0; k < 4; ++k) etb[k * 64 + lane] = z;      // 256 uint4
        uint4* sb = reinterpret_cast<uint4*>(&S_s[wv][0][0]);
        #pragma unroll
        for (int k = 0; k < 3; ++k) {
            int idx = k * 64 + lane;
            if (idx < 160) sb[idx] = z;                          // 160 uint4
        }
    }

    // ---- gather: f32 float4 loads -> f16 stores (row-major + swizzled e^T) ----
    const int* sidx = sparse_idx + row * N_SPARSE;   // uniform base
    #pragma unroll 1
    for (int q2 = lane; q2 < N_SPARSE * 16; q2 += 64) {
        int f = q2 >> 4, d4 = q2 & 15;
        int id = sidx[f];
        float4 v = *reinterpret_cast<const float4*>(
            emb + ((size_t)f * VOCAB + (size_t)id) * EMB + d4 * 4);
        auto h01 = __builtin_amdgcn_cvt_pkrtz(v.x, v.y);
        auto h23 = __builtin_amdgcn_cvt_pkrtz(v.z, v.w);
        uint2 pk;
        __builtin_memcpy(&pk.x, &h01, 4);
        __builtin_memcpy(&pk.y, &h23, 4);
        *reinterpret_cast<uint2*>(&eb_s[wv][f][d4 * 4]) = pk;    // 8B aligned
        int slot = f ^ ((d4 & 3) << 3);                          // XOR swizzle
        int d0 = d4 * 4;
        et_s[wv][d0 + 0][slot] = (unsigned short)(pk.x & 0xffffu);
        et_s[wv][d0 + 1][slot] = (unsigned short)(pk.x >> 16);
        et_s[wv][d0 + 2][slot] = (unsigned short)(pk.y & 0xffffu);
        et_s[wv][d0 + 3][slot] = (unsigned short)(pk.y >> 16);
    }

    // ---- part_1 term per lane (exact f32) ----
    float p1t = 0.0f;
    if (lane < N_DENSE) {
        p1t = dense_x[row * N_DENSE + lane] * lin_W[lane];
    } else if (lane < N_DENSE + N_SPARSE) {
        p1t = (float)sidx[lane - N_DENSE] * lin_W[lane];
    }

    // ---- W B-frags (loop-invariant, 8 VGPRs) + pred_W slices ----
    f16x8 wf[2];
    {
        const bool hok = (c16 < NH);
        const int  hc  = hok ? c16 : 0;
        #pragma unroll
        for (int kt = 0; kt < 2; ++kt) {
            union { f16x8 v; unsigned u32[4]; } u;
            #pragma unroll
            for (int jp = 0; jp < 4; ++jp) {
                int d0 = kt * 32 + q * 8 + jp * 2;
                float w0 = attn_W[d0 * NH + hc];
                float w1 = attn_W[(d0 + 1) * NH + hc];
                if (!hok) { w0 = 0.f; w1 = 0.f; }
                auto hh = __builtin_amdgcn_cvt_pkrtz(w0, w1);
                __builtin_memcpy(&u.u32[jp], &hh, 4);
            }
            wf[kt] = u.v;
        }
    }
    const float b_reg  = (c16 < NH) ? attn_b[c16] : 0.0f;
    const float pw_reg = (c16 < NH) ? proj_W[c16] : 0.0f;
    const float pb     = proj_b[0];
    float pw4[4];
    #pragma unroll
    for (int nt = 0; nt < 4; ++nt) pw4[nt] = pred_W[nt * 16 + c16];

    // ---- logit tiles: 16 pairs per tile, K=64 in 2 MFMAs; unroll 3 for ILP ----
    float lmax_h = -INFINITY;   // meaningful on lanes c16==15
    #pragma unroll 3
    for (int t = 0; t < NTILE; ++t) {
        int pc = t * 16 + c16;
        pc = pc > NPAIR - 1 ? NPAIR - 1 : pc;
        float sf = sqrtf((float)(2601 - 8 * pc));
        int i = (int)((51.0f - sf) * 0.5f);
        int st = (i * (51 - i)) >> 1;
        if (pc < st) { --i; st = (i * (51 - i)) >> 1; }
        else { int st2 = ((i + 1) * (50 - i)) >> 1; if (pc >= st2) { ++i; st = st2; } }
        int j = i + 1 + (pc - st);

        const f16x8* pi = reinterpret_cast<const f16x8*>(&eb_s[wv][i][q * 8]);
        const f16x8* pj = reinterpret_cast<const f16x8*>(&eb_s[wv][j][q * 8]);
        f16x8 ca = pi[0] * pj[0];     // cross dims q*8..+7       (kt0)
        f16x8 cb = pi[4] * pj[4];     // cross dims 32+q*8..+7    (kt1)

        f32x4 acc = {0.f, 0.f, 0.f, 0.f};
        acc = __builtin_amdgcn_mfma_f32_16x16x32_f16(ca, wf[0], acc, 0, 0, 0);
        acc = __builtin_amdgcn_mfma_f32_16x16x32_f16(cb, wf[1], acc, 0, 0, 0);

        float r0 = fmaxf(acc[0] + b_reg, 0.f) * pw_reg;
        float r1 = fmaxf(acc[1] + b_reg, 0.f) * pw_reg;
        float r2 = fmaxf(acc[2] + b_reg, 0.f) * pw_reg;
        float r3 = fmaxf(acc[3] + b_reg, 0.f) * pw_reg;
        DPP_ROWRED(r0); DPP_ROWRED(r1); DPP_ROWRED(r2); DPP_ROWRED(r3);

        if (c16 == 15) {
            float l0 = (r0 + pb) * TEMP_INV;
            float l1 = (r1 + pb) * TEMP_INV;
            float l2 = (r2 + pb) * TEMP_INV;
            float l3 = (r3 + pb) * TEMP_INV;
            lmax_h = fmaxf(lmax_h, fmaxf(fmaxf(l0, l1), fmaxf(l2, l3)));
            auto s01 = __builtin_amdgcn_cvt_pkrtz(l0, l1);
            auto s23 = __builtin_amdgcn_cvt_pkrtz(l2, l3);
            uint2 pk;
            __builtin_memcpy(&pk.x, &s01, 4);
            __builtin_memcpy(&pk.y, &s23, 4);
            *reinterpret_cast<uint2*>(&expv_s[wv][t * 16 + q * 4]) = pk;
        }
    }

    // ---- wave softmax max ----
    float gm = (c16 == 15) ? lmax_h : -INFINITY;
    #pragma unroll
    for (int o = 32; o > 0; o >>= 1) gm = fmaxf(gm, __shfl_xor(gm, o));

    // ---- exp + scatter into symmetric S (f16), accumulate sum ----
    float lsum = 0.0f;
    #pragma unroll 1
    for (int rr = 0; rr < 6; ++rr) {
        int p = rr * 64 + lane;
        if (p < NPAIR) {
            unsigned short lb = expv_s[wv][p];
            _Float16 lf;
            __builtin_memcpy(&lf, &lb, 2);
            float ev = __expf((float)lf - gm);
            lsum += ev;

            float sf = sqrtf((float)(2601 - 8 * p));
            int i = (int)((51.0f - sf) * 0.5f);
            int st = (i * (51 - i)) >> 1;
            if (p < st) { --i; st = (i * (51 - i)) >> 1; }
            else { int st2 = ((i + 1) * (50 - i)) >> 1; if (p >= st2) { ++i; st = st2; } }
            int j = i + 1 + (p - st);

            _Float16 eh = (_Float16)ev;
            unsigned short ebits;
            __builtin_memcpy(&ebits, &eh, 2);
            S_s[wv][i][j] = ebits;
            S_s[wv][j][i] = ebits;
        }
    }
    #pragma unroll
    for (int o = 32; o > 0; o >>= 1) lsum += __shfl_xor(lsum, o);

    // ---- S A-frags: two b128 row reads (diag/pads are zero) ----
    const f16x8 sfr0 = *reinterpret_cast<const f16x8*>(&S_s[wv][c16][q * 8]);
    const f16x8 sfr1 = *reinterpret_cast<const f16x8*>(&S_s[wv][16 + c16][q * 8]);

    // ---- G = S @ E (8 MFMAs) fused with att.pred_W epilogue ----
    const int ysw = ((c16 >> 2) & 3) << 3;     // et row swizzle for rows nt*16+c16
    float vsum = 0.0f;
    #pragma unroll
    for (int nt = 0; nt < 4; ++nt) {
        const unsigned short* etrow = &et_s[wv][nt * 16 + c16][0];
        const f16x8 ef = *reinterpret_cast<const f16x8*>(&etrow[(q * 8) ^ ysw]);
        f32x4 g0 = {0.f, 0.f, 0.f, 0.f};
        f32x4 g1 = {0.f, 0.f, 0.f, 0.f};
        g0 = __builtin_amdgcn_mfma_f32_16x16x32_f16(sfr0, ef, g0, 0, 0, 0);
        g1 = __builtin_amdgcn_mfma_f32_16x16x32_f16(sfr1, ef, g1, 0, 0, 0);

        ushort4 e0 = *reinterpret_cast<const ushort4*>(&etrow[(q * 4) ^ ysw]);
        ushort4 e1 = *reinterpret_cast<const ushort4*>(&etrow[(q * 4 + 16) ^ ysw]);
        float part = 0.0f;
        {
            _Float16 h;
            __builtin_memcpy(&h, &e0.x, 2); part = fmaf((float)h, g0[0], part);
            __builtin_memcpy(&h, &e0.y, 2); part = fmaf((float)h, g0[1], part);
            __builtin_memcpy(&h, &e0.z, 2); part = fmaf((float)h, g0[2], part);
            __builtin_memcpy(&h, &e0.w, 2); part = fmaf((float)h, g0[3], part);
            __builtin_memcpy(&h, &e1.x, 2); part = fmaf((float)h, g1[0], part);
            __builtin_memcpy(&h, &e1.y, 2); part = fmaf((float)h, g1[1], part);
            __builtin_memcpy(&h, &e1.z, 2); part = fmaf((float)h, g1[2], part);
            __builtin_memcpy(&h, &e1.w, 2); part = fmaf((float)h, g1[3], part);
        }
        vsum = fmaf(part, pw4[nt], vsum);
    }

    // ---- final: dual wave reduce (0.5x fixes symmetric double count) ----
    float p1 = p1t;
    #pragma unroll
    for (int o = 32; o > 0; o >>= 1) {
        vsum += __shfl_xor(vsum, o);
        p1   += __shfl_xor(p1, o);
    }
    if (lane == 0) {
        float z = p1 + lin_b[0] + 0.5f * vsum / lsum + pred_b[0];
        out[row] = 1.0f / (1.0f + __expf(-z));
    }
}

extern "C" void kernel_launch(void* const* d_in, const int* in_sizes, int n_in,
                              void* d_out, int out_size, void* d_ws, size_t ws_size,
                              hipStream_t stream)
{
    const float* dense_x = (const float*)d_in[0];
    const int*   sparse  = (const int*)  d_in[1];
    const float* emb     = (const float*)d_in[2];
    const float* attn_W  = (const float*)d_in[3];
    const float* attn_b  = (const float*)d_in[4];
    const float* proj_W  = (const float*)d_in[5];
    const float* proj_b  = (const float*)d_in[6];
    const float* lin_W   = (const float*)d_in[7];
    const float* lin_b   = (const float*)d_in[8];
    const float* pred_W  = (const float*)d_in[9];
    const float* pred_b  = (const float*)d_in[10];
    float* out = (float*)d_out;

    int rows = in_sizes[0] / N_DENSE;   // 8192
    afm_kernel<<<rows / 2, 128, 0, stream>>>(dense_x, sparse, emb, attn_W, attn_b,
                                             proj_W, proj_b, lin_W, lin_b,
                                             pred_W, pred_b, out);
}

// Round 8
// 40.266 us; speedup vs baseline: 1.3885x; 1.3885x over previous
//
#include <hip/hip_runtime.h>
#include <math.h>

#define N_DENSE  13
#define N_SPARSE 26
#define VOCAB    100000
#define EMB      64
#define NH       12
#define NPAIR    325
#define NTILE    21      // ceil(325/16) pair tiles
#define EBSTR    72      // u16 per eb row: 144B (16B-aligned); S aliases this region
#define ETSTR    32      // u16 per et row: 64B, XOR-swizzled slots
#define SSTR     40      // u16 per S row: 80B (aliased over eb_s)
#define NPADH    336     // logit slots (21*16)
#define GITER    7       // ceil(26*16/64) gather rounds
#define TEMP_INV 10.0f

typedef __attribute__((ext_vector_type(8))) _Float16 f16x8;
typedef __attribute__((ext_vector_type(4))) float    f32x4;

// DPP row_shr reduction within each 16-lane row; result lands in lane (row base + 15).
#define DPP_STEP(x, ctrl)                                                        \
    x += __int_as_float(__builtin_amdgcn_update_dpp(                            \
            0, __float_as_int(x), ctrl, 0xF, 0xF, true))
#define DPP_ROWRED(x) do { DPP_STEP(x, 0x111); DPP_STEP(x, 0x112);              \
                           DPP_STEP(x, 0x114); DPP_STEP(x, 0x118); } while (0)

__global__ __launch_bounds__(128, 4) void afm_kernel(
    const float* __restrict__ dense_x,
    const int*   __restrict__ sparse_idx,
    const float* __restrict__ emb,
    const float* __restrict__ attn_W,
    const float* __restrict__ attn_b,
    const float* __restrict__ proj_W,
    const float* __restrict__ proj_b,
    const float* __restrict__ lin_W,
    const float* __restrict__ lin_b,
    const float* __restrict__ pred_W,
    const float* __restrict__ pred_b,
    float* __restrict__ out)
{
    const int tid  = threadIdx.x;
    const int lane = tid & 63;
    const int wv   = tid >> 6;        // wave = row slot (2 rows/block)
    const int q    = lane >> 4;       // MFMA k-group
    const int c16  = lane & 15;       // MFMA row/col-16 index
    const int row  = __builtin_amdgcn_readfirstlane(blockIdx.x * 2 + wv);

    __shared__ __align__(16) unsigned short eb_s[2][N_SPARSE][EBSTR]; // e row-major; S aliases
    __shared__ __align__(16) unsigned short et_s[2][EMB][ETSTR];      // e^T f16, XOR-swz
    __shared__ __align__(16) unsigned short expv_s[2][NPADH];         // parked logits f16
    __shared__ __align__(16) unsigned short ptab_s[NPADH];            // pair (i | j<<8), block-shared

    // ---- 1: prefetch sparse ids (one coalesced load) ----
    const int* sidx = sparse_idx + row * N_SPARSE;   // uniform base
    int myid = (lane < N_SPARSE) ? sidx[lane] : 0;

    // ---- 2: issue ALL 7 embedding float4 loads back-to-back (latency pipelining) ----
    float4 vg[GITER];
    int ffk[GITER], ddk[GITER];
    #pragma unroll
    for (int k = 0; k < GITER; ++k) {
        int q2  = lane + 64 * k;
        int q2c = q2 < N_SPARSE * 16 ? q2 : N_SPARSE * 16 - 1;
        ffk[k] = q2c >> 4;
        ddk[k] = q2c & 15;
        int idk = __shfl(myid, ffk[k]);
        vg[k] = *(reinterpret_cast<const float4*>(
                    emb + ((size_t)ffk[k] * VOCAB + (size_t)idk) * EMB) + ddk[k]);
    }

    // ---- 3: W B-frags + params (independent L2 loads; overlap gather latency) ----
    f16x8 wf[2];
    {
        const bool hok = (c16 < NH);
        const int  hc  = hok ? c16 : 0;
        #pragma unroll
        for (int kt = 0; kt < 2; ++kt) {
            union { f16x8 v; unsigned u32[4]; } u;
            #pragma unroll
            for (int jp = 0; jp < 4; ++jp) {
                int d0 = kt * 32 + q * 8 + jp * 2;
                float w0 = attn_W[d0 * NH + hc];
                float w1 = attn_W[(d0 + 1) * NH + hc];
                if (!hok) { w0 = 0.f; w1 = 0.f; }
                auto hh = __builtin_amdgcn_cvt_pkrtz(w0, w1);
                __builtin_memcpy(&u.u32[jp], &hh, 4);
            }
            wf[kt] = u.v;
        }
    }
    const float b_reg  = (c16 < NH) ? attn_b[c16] : 0.0f;
    const float pw_reg = (c16 < NH) ? proj_W[c16] : 0.0f;
    const float pb     = proj_b[0];
    float pw4[4];
    #pragma unroll
    for (int nt = 0; nt < 4; ++nt) pw4[nt] = pred_W[nt * 16 + c16];

    // ---- 4: pair table (block-cooperative VALU; overlaps load latency) ----
    #pragma unroll 1
    for (int p = tid; p < NPADH; p += 128) {
        int pc = p < NPAIR ? p : NPAIR - 1;
        float sf = sqrtf((float)(2601 - 8 * pc));
        int i = (int)((51.0f - sf) * 0.5f);
        int st = (i * (51 - i)) >> 1;
        if (pc < st) { --i; st = (i * (51 - i)) >> 1; }
        else { int st2 = ((i + 1) * (50 - i)) >> 1; if (pc >= st2) { ++i; st = st2; } }
        int j = i + 1 + (pc - st);
        ptab_s[p] = (unsigned short)(i | (j << 8));
    }

    // ---- 5: part_1 term per lane (exact f32; ids via shuffle) ----
    int srcf = lane - N_DENSE;
    int idsh = __shfl(myid, (srcf >= 0 && srcf < N_SPARSE) ? srcf : 0);
    float p1t = 0.0f;
    if (lane < N_DENSE) {
        p1t = dense_x[row * N_DENSE + lane] * lin_W[lane];
    } else if (lane < N_DENSE + N_SPARSE) {
        p1t = (float)idsh * lin_W[lane];
    }

    // ---- 6: zero et (pads must be 0 for PV K-reach) ----
    {
        const uint4 z = {0u, 0u, 0u, 0u};
        uint4* etb = reinterpret_cast<uint4*>(&et_s[wv][0][0]);
        #pragma unroll
        for (int k2 = 0; k2 < 4; ++k2) etb[k2 * 64 + lane] = z;   // 256 uint4
    }

    // ---- 7: gather stores (single vmcnt wait drains all 7) ----
    #pragma unroll
    for (int k = 0; k < GITER; ++k) {
        if (lane + 64 * k < N_SPARSE * 16) {
            int f = ffk[k], d4 = ddk[k];
            auto h01 = __builtin_amdgcn_cvt_pkrtz(vg[k].x, vg[k].y);
            auto h23 = __builtin_amdgcn_cvt_pkrtz(vg[k].z, vg[k].w);
            uint2 pk;
            __builtin_memcpy(&pk.x, &h01, 4);
            __builtin_memcpy(&pk.y, &h23, 4);
            *reinterpret_cast<uint2*>(&eb_s[wv][f][d4 * 4]) = pk;   // 8B aligned
            int slot = f ^ ((d4 & 3) << 3);                         // XOR swizzle
            int d0 = d4 * 4;
            et_s[wv][d0 + 0][slot] = (unsigned short)(pk.x & 0xffffu);
            et_s[wv][d0 + 1][slot] = (unsigned short)(pk.x >> 16);
            et_s[wv][d0 + 2][slot] = (unsigned short)(pk.y & 0xffffu);
            et_s[wv][d0 + 3][slot] = (unsigned short)(pk.y >> 16);
        }
    }

    __syncthreads();   // publishes ptab_s (only cross-wave dependency)

    // ---- 8: logit tiles: 16 pairs per tile, K=64 in 2 MFMAs ----
    float lmax_h = -INFINITY;   // meaningful on lanes c16==15
    #pragma unroll 3
    for (int t = 0; t < NTILE; ++t) {
        unsigned pt = ptab_s[t * 16 + c16];
        int i = pt & 0xff, j = pt >> 8;

        const f16x8* pi = reinterpret_cast<const f16x8*>(&eb_s[wv][0][0] + i * EBSTR) + q;
        const f16x8* pj = reinterpret_cast<const f16x8*>(&eb_s[wv][0][0] + j * EBSTR) + q;
        f16x8 ca = pi[0] * pj[0];     // cross dims q*8..+7       (kt0)
        f16x8 cb = pi[4] * pj[4];     // cross dims 32+q*8..+7    (kt1)

        f32x4 acc = {0.f, 0.f, 0.f, 0.f};
        acc = __builtin_amdgcn_mfma_f32_16x16x32_f16(ca, wf[0], acc, 0, 0, 0);
        acc = __builtin_amdgcn_mfma_f32_16x16x32_f16(cb, wf[1], acc, 0, 0, 0);

        float r0 = fmaxf(acc[0] + b_reg, 0.f) * pw_reg;
        float r1 = fmaxf(acc[1] + b_reg, 0.f) * pw_reg;
        float r2 = fmaxf(acc[2] + b_reg, 0.f) * pw_reg;
        float r3 = fmaxf(acc[3] + b_reg, 0.f) * pw_reg;
        DPP_ROWRED(r0); DPP_ROWRED(r1); DPP_ROWRED(r2); DPP_ROWRED(r3);

        if (c16 == 15) {
            float l0 = (r0 + pb) * TEMP_INV;
            float l1 = (r1 + pb) * TEMP_INV;
            float l2 = (r2 + pb) * TEMP_INV;
            float l3 = (r3 + pb) * TEMP_INV;
            lmax_h = fmaxf(lmax_h, fmaxf(fmaxf(l0, l1), fmaxf(l2, l3)));
            auto s01 = __builtin_amdgcn_cvt_pkrtz(l0, l1);
            auto s23 = __builtin_amdgcn_cvt_pkrtz(l2, l3);
            uint2 pk;
            __builtin_memcpy(&pk.x, &s01, 4);
            __builtin_memcpy(&pk.y, &s23, 4);
            *reinterpret_cast<uint2*>(&expv_s[wv][t * 16 + q * 4]) = pk;
        }
    }

    // ---- 9: wave softmax max ----
    float gm = (c16 == 15) ? lmax_h : -INFINITY;
    #pragma unroll
    for (int o = 32; o > 0; o >>= 1) gm = fmaxf(gm, __shfl_xor(gm, o));

    // ---- 10: zero S (aliased over now-dead eb), exp + symmetric scatter + sum ----
    unsigned short* Sb = &eb_s[wv][0][0];       // [32][SSTR] u16, 2560 B
    {
        const uint4 z = {0u, 0u, 0u, 0u};
        uint4* sb = reinterpret_cast<uint4*>(Sb);
        #pragma unroll
        for (int k2 = 0; k2 < 3; ++k2) {
            int idx = k2 * 64 + lane;
            if (idx < 160) sb[idx] = z;
        }
    }
    float lsum = 0.0f;
    #pragma unroll 1
    for (int rr = 0; rr < 6; ++rr) {
        int p = rr * 64 + lane;
        if (p < NPAIR) {
            unsigned short lb = expv_s[wv][p];
            _Float16 lf;
            __builtin_memcpy(&lf, &lb, 2);
            float ev = __expf((float)lf - gm);
            lsum += ev;
            unsigned pt = ptab_s[p];
            int i = pt & 0xff, j = pt >> 8;
            _Float16 eh = (_Float16)ev;
            unsigned short ebits;
            __builtin_memcpy(&ebits, &eh, 2);
            Sb[i * SSTR + j] = ebits;
            Sb[j * SSTR + i] = ebits;
        }
    }
    #pragma unroll
    for (int o = 32; o > 0; o >>= 1) lsum += __shfl_xor(lsum, o);

    // ---- 11: S A-frags (diag/pads zero) ----
    const f16x8 sfr0 = *reinterpret_cast<const f16x8*>(Sb + c16 * SSTR + q * 8);
    const f16x8 sfr1 = *reinterpret_cast<const f16x8*>(Sb + (16 + c16) * SSTR + q * 8);

    // ---- 12: G = S @ E (8 MFMAs) fused with att.pred_W epilogue ----
    const int ysw = ((c16 >> 2) & 3) << 3;     // et row swizzle for rows nt*16+c16
    float vsum = 0.0f;
    #pragma unroll
    for (int nt = 0; nt < 4; ++nt) {
        const unsigned short* etrow = &et_s[wv][nt * 16 + c16][0];
        const f16x8 ef = *reinterpret_cast<const f16x8*>(&etrow[(q * 8) ^ ysw]);
        f32x4 g0 = {0.f, 0.f, 0.f, 0.f};
        f32x4 g1 = {0.f, 0.f, 0.f, 0.f};
        g0 = __builtin_amdgcn_mfma_f32_16x16x32_f16(sfr0, ef, g0, 0, 0, 0);
        g1 = __builtin_amdgcn_mfma_f32_16x16x32_f16(sfr1, ef, g1, 0, 0, 0);

        ushort4 e0 = *reinterpret_cast<const ushort4*>(&etrow[(q * 4) ^ ysw]);
        ushort4 e1 = *reinterpret_cast<const ushort4*>(&etrow[(q * 4 + 16) ^ ysw]);
        float part = 0.0f;
        {
            _Float16 h;
            __builtin_memcpy(&h, &e0.x, 2); part = fmaf((float)h, g0[0], part);
            __builtin_memcpy(&h, &e0.y, 2); part = fmaf((float)h, g0[1], part);
            __builtin_memcpy(&h, &e0.z, 2); part = fmaf((float)h, g0[2], part);
            __builtin_memcpy(&h, &e0.w, 2); part = fmaf((float)h, g0[3], part);
            __builtin_memcpy(&h, &e1.x, 2); part = fmaf((float)h, g1[0], part);
            __builtin_memcpy(&h, &e1.y, 2); part = fmaf((float)h, g1[1], part);
            __builtin_memcpy(&h, &e1.z, 2); part = fmaf((float)h, g1[2], part);
            __builtin_memcpy(&h, &e1.w, 2); part = fmaf((float)h, g1[3], part);
        }
        vsum = fmaf(part, pw4[nt], vsum);
    }

    // ---- 13: dual wave reduce (0.5x fixes symmetric double count), sigmoid ----
    float p1 = p1t;
    #pragma unroll
    for (int o = 32; o > 0; o >>= 1) {
        vsum += __shfl_xor(vsum, o);
        p1   += __shfl_xor(p1, o);
    }
    if (lane == 0) {
        float z = p1 + lin_b[0] + 0.5f * vsum / lsum + pred_b[0];
        out[row] = 1.0f / (1.0f + __expf(-z));
    }
}

extern "C" void kernel_launch(void* const* d_in, const int* in_sizes, int n_in,
                              void* d_out, int out_size, void* d_ws, size_t ws_size,
                              hipStream_t stream)
{
    const float* dense_x = (const float*)d_in[0];
    const int*   sparse  = (const int*)  d_in[1];
    const float* emb     = (const float*)d_in[2];
    const float* attn_W  = (const float*)d_in[3];
    const float* attn_b  = (const float*)d_in[4];
    const float* proj_W  = (const float*)d_in[5];
    const float* proj_b  = (const float*)d_in[6];
    const float* lin_W   = (const float*)d_in[7];
    const float* lin_b   = (const float*)d_in[8];
    const float* pred_W  = (const float*)d_in[9];
    const float* pred_b  = (const float*)d_in[10];
    float* out = (float*)d_out;

    int rows = in_sizes[0] / N_DENSE;   // 8192
    afm_kernel<<<rows / 2, 128, 0, stream>>>(dense_x, sparse, emb, attn_W, attn_b,
                                             proj_W, proj_b, lin_W, lin_b,
                                             pred_W, pred_b, out);
}